// Round 1
// 137.536 us; speedup vs baseline: 1.0388x; 1.0388x over previous
//
#include <hip/hip_runtime.h>
#include <stdint.h>

// TypedLinear: out[i] = W[types[i]] @ x[i] + b[types[i]]
// N=65536, IN=OUT=256, T=8, fp32 in/out. bf16-MFMA grouped-GEMM via type bucketing.
// This rev: exact tile grid (no dead blocks), 4 blocks/CU occupancy target,
// B-before-A staging order, fused prep+bucket.

#define NROWS 65536
#define NTYPES 8
#define KDIM 256
#define ODIM 256
#define BM 128
#define BN 128
#define BK 64
#define MAX_TILES (NROWS / BM + NTYPES - 1)   // 519: worst-case sum of ceil(cnt_t/BM)

typedef __attribute__((ext_vector_type(8))) short short8;
typedef __attribute__((ext_vector_type(4))) float f32x4;

__device__ __forceinline__ unsigned short f2bf(float f) {
    // round-to-nearest-even fp32 -> bf16
    unsigned int u = __float_as_uint(f);
    u += 0x7fffu + ((u >> 16) & 1u);
    return (unsigned short)(u >> 16);
}

// ---------------- fused prep + bucket ----------------
// blocks [0,512): W fp32 -> bf16 (one float4/thread, 8*256*256/4 = 131072 total)
// blocks [512,768): per-type index lists via LDS histogram -> 8 global atomics/block
// cnt is pre-zeroed by a hipMemsetAsync before this kernel.
__global__ void prep_bucket_kernel(const float* __restrict__ W,
                                   unsigned short* __restrict__ Wb,
                                   const int* __restrict__ types,
                                   int* __restrict__ cnt,
                                   int* __restrict__ idx) {
    const int b = blockIdx.x;
    if (b < 512) {
        int i = b * 256 + threadIdx.x;
        float4 v = ((const float4*)W)[i];
        ushort4 p;
        p.x = f2bf(v.x); p.y = f2bf(v.y); p.z = f2bf(v.z); p.w = f2bf(v.w);
        ((ushort4*)Wb)[i] = p;
    } else {
        __shared__ int h[NTYPES];
        __shared__ int base[NTYPES];
        int i = (b - 512) * 256 + threadIdx.x;
        if (threadIdx.x < NTYPES) h[threadIdx.x] = 0;
        __syncthreads();
        int t = types[i];
        int r = atomicAdd(&h[t], 1);
        __syncthreads();
        if (threadIdx.x < NTYPES)
            base[threadIdx.x] = atomicAdd(&cnt[threadIdx.x], h[threadIdx.x]);
        __syncthreads();
        idx[t * NROWS + base[t] + r] = i;
    }
}

// ---------------- grouped GEMM ----------------
// grid (MAX_TILES, 2): flat m-tile id -> (type, m0) via prefix over cnt[8].
// 256 threads = 4 waves (2x2 of 64x64). As/Bs are [128 rows][64 bf16] with
// 16B-chunk XOR swizzle: chunk' = chunk ^ (row&7).
__global__ __launch_bounds__(256, 4)
void gemm_kernel(const float* __restrict__ x,
                 const float* __restrict__ bias,
                 const unsigned short* __restrict__ Wb,
                 const int* __restrict__ cnt,
                 const int* __restrict__ idx,
                 float* __restrict__ out) {
    // ---- flat tile id -> (type t, tile base m0); uniform scalar work
    const int bid = blockIdx.x;
    int t = -1, m0 = 0, count = 0, accum = 0;
    #pragma unroll
    for (int i = 0; i < NTYPES; ++i) {
        int c = cnt[i];
        int ntile = (c + BM - 1) / BM;
        if (t < 0 && bid < accum + ntile) { t = i; m0 = (bid - accum) * BM; count = c; }
        accum += ntile;
    }
    if (t < 0) return;                 // only a handful of tail blocks
    const int n0 = blockIdx.y * BN;

    __shared__ int idx_s[BM];
    __shared__ float bias_s[BN];
    __shared__ unsigned short As[BM * BK];   // 16 KB, swizzled
    __shared__ unsigned short Bs[BN * BK];   // 16 KB, swizzled

    const int tid = threadIdx.x;

    if (tid < BM) {
        int m = m0 + tid;
        idx_s[tid] = (m < count) ? idx[t * NROWS + m] : 0;
    } else {
        bias_s[tid - BM] = bias[t * ODIM + n0 + (tid - BM)];
    }
    __syncthreads();

    const int wave = tid >> 6;
    const int lane = tid & 63;
    const int lr = lane & 15;   // A-row / B-row / D-col within 16
    const int lq = lane >> 4;   // quad
    const int wm = (wave >> 1) * 64;
    const int wn = (wave & 1) * 64;

    f32x4 acc[4][4] = {};

    // A staging mapping: 16 threads per row, float4 each; 16 rows per sub-iter
    const int srow = tid >> 4;       // 0..15
    const int sc   = tid & 15;       // float4 slot within the 64-float row chunk

    char* AsB = (char*)As;
    char* BsB = (char*)Bs;

    for (int k0 = 0; k0 < KDIM; k0 += BK) {
        // ---- stage B FIRST (no register dependency): global_load_lds 16B/lane.
        // dest = wave-uniform base + lane*16; swizzle applied on the SOURCE address.
        #pragma unroll
        for (int it = 0; it < 4; ++it) {
            int dbyte = wave * 4096 + it * 1024;           // wave-uniform LDS base
            int drow  = (dbyte >> 7) + (lane >> 3);        // row this lane fills
            int schunk = (lane & 7) ^ (lane >> 3);         // (chunk) ^ (row & 7)
            const unsigned short* src =
                Wb + (size_t)(t * ODIM + n0 + drow) * KDIM + k0 + schunk * 8;
            __builtin_amdgcn_global_load_lds(
                (const __attribute__((address_space(1))) void*)src,
                (__attribute__((address_space(3))) void*)(BsB + dbyte),
                16, 0, 0);
        }
        // ---- stage A: issue ALL 8 gather loads, then convert+write (loads overlap)
        float4 av[8];
        #pragma unroll
        for (int j = 0; j < 8; ++j) {
            int row = j * 16 + srow;
            av[j] = *(const float4*)(x + (size_t)idx_s[row] * KDIM + k0 + sc * 4);
        }
        #pragma unroll
        for (int j = 0; j < 8; ++j) {
            int row = j * 16 + srow;
            ushort4 p;
            p.x = f2bf(av[j].x); p.y = f2bf(av[j].y);
            p.z = f2bf(av[j].z); p.w = f2bf(av[j].w);
            int ch = (sc >> 1) ^ (row & 7);
            *(ushort4*)(AsB + row * 128 + ch * 16 + (sc & 1) * 8) = p;
        }
        __syncthreads();

        // ---- compute: 2 x (4 A-frags, 4 B-frags, 16 MFMAs)
        #pragma unroll
        for (int kh = 0; kh < 2; ++kh) {      // k-half: chunk base 0 or 4
            short8 af[4], bf[4];
            #pragma unroll
            for (int i = 0; i < 4; ++i) {
                int arow = wm + i * 16 + lr;
                int ach = ((kh << 2) + lq) ^ (arow & 7);
                af[i] = *(const short8*)(AsB + arow * 128 + ach * 16);
            }
            #pragma unroll
            for (int i = 0; i < 4; ++i) {
                int brow = wn + i * 16 + lr;
                int bch = ((kh << 2) + lq) ^ (brow & 7);
                bf[i] = *(const short8*)(BsB + brow * 128 + bch * 16);
            }
            #pragma unroll
            for (int i = 0; i < 4; ++i)
                #pragma unroll
                for (int j = 0; j < 4; ++j)
                    acc[i][j] = __builtin_amdgcn_mfma_f32_16x16x32_bf16(
                        af[i], bf[j], acc[i][j], 0, 0, 0);
        }
        __syncthreads();
    }

    // ---- epilogue: D col = lane&15, row = (lane>>4)*4 + reg
    #pragma unroll
    for (int i = 0; i < 4; ++i) {
        int lmBase = wm + i * 16 + lq * 4;
        #pragma unroll
        for (int r = 0; r < 4; ++r) {
            int lm = lmBase + r;
            if (m0 + lm < count) {
                size_t orow = (size_t)idx_s[lm] * ODIM;
                #pragma unroll
                for (int j = 0; j < 4; ++j) {
                    int col = wn + j * 16 + lr;
                    out[orow + n0 + col] = acc[i][j][r] + bias_s[col];
                }
            }
        }
    }
}

extern "C" void kernel_launch(void* const* d_in, const int* in_sizes, int n_in,
                              void* d_out, int out_size, void* d_ws, size_t ws_size,
                              hipStream_t stream) {
    const float* x     = (const float*)d_in[0];
    const int*   types = (const int*)d_in[1];
    const float* W     = (const float*)d_in[2];
    const float* b     = (const float*)d_in[3];
    float* out = (float*)d_out;

    // ws layout: [0,32) cnt | [1024, 1024+2MB) idx | then 1MB bf16 W  (~3.1 MB total)
    char* ws = (char*)d_ws;
    int* cnt = (int*)ws;
    int* idx = (int*)(ws + 1024);
    unsigned short* Wb = (unsigned short*)(ws + 1024 + (size_t)NTYPES * NROWS * sizeof(int));

    hipMemsetAsync(cnt, 0, NTYPES * sizeof(int), stream);
    prep_bucket_kernel<<<768, 256, 0, stream>>>(W, Wb, types, cnt, idx);
    dim3 grid(MAX_TILES, ODIM / BN);
    gemm_kernel<<<grid, 256, 0, stream>>>(x, b, Wb, cnt, idx, out);
}

// Round 2
// 134.538 us; speedup vs baseline: 1.0619x; 1.0223x over previous
//
#include <hip/hip_runtime.h>
#include <stdint.h>

// TypedLinear: out[i] = W[types[i]] @ x[i] + b[types[i]]
// N=65536, IN=OUT=256, T=8, fp32 in/out. bf16-MFMA grouped-GEMM via type bucketing.
// This rev: BM=64 x BN=256 tiles (x read ONCE), W pre-packed into MFMA-fragment
// order and read straight from L2 (no B LDS staging, no global_load_lds),
// full-K A staging with a SINGLE barrier per block.

#define NROWS 65536
#define NTYPES 8
#define KDIM 256
#define ODIM 256
#define BM 64
#define MAX_TILES (NROWS / BM + NTYPES - 1)   // 1031 worst case

typedef __attribute__((ext_vector_type(8))) short short8;
typedef __attribute__((ext_vector_type(4))) float f32x4;

__device__ __forceinline__ unsigned short f2bf(float f) {
    // round-to-nearest-even fp32 -> bf16
    unsigned int u = __float_as_uint(f);
    u += 0x7fffu + ((u >> 16) & 1u);
    return (unsigned short)(u >> 16);
}

// ---------------- fused prep + bucket ----------------
// blocks [0,256): pack W fp32 -> bf16 in MFMA-fragment order:
//   record g = ((t*16 + f)*8 + q)  (f = out-col frag 0..15, q = k32-chunk 0..7)
//   Wp[g*512 + l*8 + e] = bf16( W[t][f*16 + (l&15)][q*32 + (l>>4)*8 + e] )
//   so a frag load is one coalesced 16B/lane read (1 KB/wave).
// blocks [256,512): per-type index lists via LDS histogram -> 8 global atomics.
// cnt pre-zeroed by hipMemsetAsync.
__global__ void prep_bucket_kernel(const float* __restrict__ W,
                                   unsigned short* __restrict__ Wp,
                                   const int* __restrict__ types,
                                   int* __restrict__ cnt,
                                   int* __restrict__ idx) {
    const int b = blockIdx.x;
    if (b < 256) {
        const int gid = b * 256 + threadIdx.x;      // 0..65535 lane-records
        const int t = gid >> 13;
        const int rem = gid & 8191;
        const int f = rem >> 9;                     // 0..15
        const int q = (rem >> 6) & 7;               // 0..7
        const int l = rem & 63;                     // lane
        const float* src = W + ((size_t)t * ODIM + f * 16 + (l & 15)) * KDIM
                             + q * 32 + (l >> 4) * 8;
        const float4 v0 = *(const float4*)src;
        const float4 v1 = *(const float4*)(src + 4);
        ushort4 p0, p1;
        p0.x = f2bf(v0.x); p0.y = f2bf(v0.y); p0.z = f2bf(v0.z); p0.w = f2bf(v0.w);
        p1.x = f2bf(v1.x); p1.y = f2bf(v1.y); p1.z = f2bf(v1.z); p1.w = f2bf(v1.w);
        ushort4* dst = (ushort4*)(Wp + (size_t)gid * 8);
        dst[0] = p0; dst[1] = p1;
    } else {
        __shared__ int h[NTYPES];
        __shared__ int base[NTYPES];
        int i = (b - 256) * 256 + threadIdx.x;
        if (threadIdx.x < NTYPES) h[threadIdx.x] = 0;
        __syncthreads();
        int t = types[i];
        int r = atomicAdd(&h[t], 1);
        __syncthreads();
        if (threadIdx.x < NTYPES)
            base[threadIdx.x] = atomicAdd(&cnt[threadIdx.x], h[threadIdx.x]);
        __syncthreads();
        idx[t * NROWS + base[t] + r] = i;
    }
}

// ---------------- grouped GEMM ----------------
// grid (MAX_TILES): flat m-tile -> (type, m0). 256 threads = 4 waves, each wave
// owns 64 output cols (wn = wave*64), all share the 64-row A tile.
// As: [64 rows][256 k] bf16, 16B-chunk XOR swizzle c' = c ^ (row&7).
// B frags: coalesced short8 loads from packed Wp (L2-resident, 1 MB total).
__global__ __launch_bounds__(256, 4)
void gemm_kernel(const float* __restrict__ x,
                 const float* __restrict__ bias,
                 const unsigned short* __restrict__ Wp,
                 const int* __restrict__ cnt,
                 const int* __restrict__ idx,
                 float* __restrict__ out) {
    // ---- flat tile id -> (type t, tile base m0); uniform scalar work
    const int bid = blockIdx.x;
    int t = -1, m0 = 0, count = 0, accum = 0;
    #pragma unroll
    for (int i = 0; i < NTYPES; ++i) {
        int c = cnt[i];
        int ntile = (c + BM - 1) / BM;
        if (t < 0 && bid < accum + ntile) { t = i; m0 = (bid - accum) * BM; count = c; }
        accum += ntile;
    }
    if (t < 0) return;                 // only a handful of tail blocks

    __shared__ unsigned short As[BM * KDIM];    // 32 KB, swizzled
    char* AsB = (char*)As;

    const int tid = threadIdx.x;
    const int srow = tid >> 4;       // 0..15
    const int sc   = tid & 15;

    // ---- stage A: 64 rows x 256 fp32 -> bf16 LDS, one burst, one barrier.
    // 16-lane groups read 256B contiguous per row; idx loads broadcast per group.
    #pragma unroll
    for (int p = 0; p < 4; ++p) {
        const int row = p * 16 + srow;
        const int gr = m0 + row;
        const int xr = idx[t * NROWS + (gr < count ? gr : count - 1)];
        const float* xs = x + (size_t)xr * KDIM;
        #pragma unroll
        for (int s = 0; s < 4; ++s) {
            const int slot = s * 16 + sc;            // float4 slot 0..63
            const float4 v = *(const float4*)(xs + slot * 4);
            ushort4 pk;
            pk.x = f2bf(v.x); pk.y = f2bf(v.y); pk.z = f2bf(v.z); pk.w = f2bf(v.w);
            const int c = slot >> 1;                 // 16B chunk 0..31
            *(ushort4*)(AsB + row * 512 + (c ^ (row & 7)) * 16 + (slot & 1) * 8) = pk;
        }
    }
    __syncthreads();

    const int wave = tid >> 6;       // 0..3, owns cols [wave*64, wave*64+64)
    const int lane = tid & 63;
    const int lr = lane & 15;
    const int lq = lane >> 4;

    const unsigned short* Wpt = Wp + (size_t)t * 16 * 8 * 512;   // type base

    f32x4 acc[4][4] = {};

    // ---- compute: 8 k32-chunks x 16 MFMAs; B frags streamed from L2.
    #pragma unroll
    for (int q = 0; q < 8; ++q) {
        short8 bf[4], af[4];
        #pragma unroll
        for (int j = 0; j < 4; ++j)
            bf[j] = *(const short8*)(Wpt + ((size_t)((wave * 4 + j) * 8 + q)) * 512
                                         + lane * 8);
        #pragma unroll
        for (int i = 0; i < 4; ++i) {
            const int row = i * 16 + lr;
            af[i] = *(const short8*)(AsB + row * 512
                                         + (((q << 2) + lq) ^ (row & 7)) * 16);
        }
        #pragma unroll
        for (int i = 0; i < 4; ++i)
            #pragma unroll
            for (int j = 0; j < 4; ++j)
                acc[i][j] = __builtin_amdgcn_mfma_f32_16x16x32_bf16(
                    af[i], bf[j], acc[i][j], 0, 0, 0);
    }

    // ---- epilogue: D col = lane&15, row = (lane>>4)*4 + reg
    float bv[4];
    #pragma unroll
    for (int j = 0; j < 4; ++j)
        bv[j] = bias[t * ODIM + wave * 64 + j * 16 + lr];

    #pragma unroll
    for (int i = 0; i < 4; ++i) {
        #pragma unroll
        for (int r = 0; r < 4; ++r) {
            const int lm = i * 16 + lq * 4 + r;
            const int gr = m0 + lm;
            if (gr < count) {
                const size_t orow = (size_t)idx[t * NROWS + gr] * ODIM;
                #pragma unroll
                for (int j = 0; j < 4; ++j)
                    out[orow + wave * 64 + j * 16 + lr] = acc[i][j][r] + bv[j];
            }
        }
    }
}

extern "C" void kernel_launch(void* const* d_in, const int* in_sizes, int n_in,
                              void* d_out, int out_size, void* d_ws, size_t ws_size,
                              hipStream_t stream) {
    const float* x     = (const float*)d_in[0];
    const int*   types = (const int*)d_in[1];
    const float* W     = (const float*)d_in[2];
    const float* b     = (const float*)d_in[3];
    float* out = (float*)d_out;

    // ws layout: [0,32) cnt | [1024, 1024+2MB) idx | then 1MB packed bf16 W
    char* ws = (char*)d_ws;
    int* cnt = (int*)ws;
    int* idx = (int*)(ws + 1024);
    unsigned short* Wp = (unsigned short*)(ws + 1024 + (size_t)NTYPES * NROWS * sizeof(int));

    hipMemsetAsync(cnt, 0, NTYPES * sizeof(int), stream);
    prep_bucket_kernel<<<512, 256, 0, stream>>>(W, Wp, types, cnt, idx);
    gemm_kernel<<<MAX_TILES, 256, 0, stream>>>(x, b, Wp, cnt, idx, out);
}